// Round 7
// baseline (261.555 us; speedup 1.0000x reference)
//
#include <hip/hip_runtime.h>

typedef float f32x4 __attribute__((ext_vector_type(4)));
typedef short bf16x8 __attribute__((ext_vector_type(8)));

#define SDT_BATCH 65536

__device__ __forceinline__ unsigned short f2bf(float f) {
    union { float f; unsigned int u; } x; x.f = f;
    unsigned int r = (x.u + 0x7fffu + ((x.u >> 16) & 1u)) >> 16;
    return (unsigned short)r;
}
__device__ __forceinline__ float bf2f(unsigned short h) {
    union { unsigned int u; float f; } x; x.u = ((unsigned int)h) << 16;
    return x.f;
}
__device__ __forceinline__ float bfu_lo(unsigned int u) {
    union { unsigned int i; float f; } x; x.i = u << 16; return x.f;
}
__device__ __forceinline__ float bfu_hi(unsigned int u) {
    union { unsigned int i; float f; } x; x.i = u & 0xffff0000u; return x.f;
}

// swizzled byte offset into the 16-row x 2048B LDS panel
__device__ __forceinline__ int lswz(int row, int b) {
    return row * 2048 + (b ^ ((row & 7) << 4) ^ (((b >> 7) & 7) << 4));
}

// ---------------------------------------------------------------------------
// k_prep: Wi [1023][128] f32 -> Wib [1024][128] bf16 (row 1023 zero),
//         Wl [32][1024] f32 -> Wlb bf16, zero Sleaf[1024].
// ---------------------------------------------------------------------------
__global__ __launch_bounds__(256) void k_prep(const float* __restrict__ Wi,
                                              const float* __restrict__ Wl,
                                              unsigned short* __restrict__ Wib,
                                              unsigned short* __restrict__ Wlb,
                                              float* __restrict__ Sleaf) {
    int i = blockIdx.x * 256 + threadIdx.x;   // 161*256 = 41216 slots
    if (i < 32736) {
        float4 v = ((const float4*)Wi)[i];
        ushort4 w; w.x = f2bf(v.x); w.y = f2bf(v.y); w.z = f2bf(v.z); w.w = f2bf(v.w);
        ((ushort4*)Wib)[i] = w;
    } else if (i < 32768) {
        ushort4 z; z.x = 0; z.y = 0; z.z = 0; z.w = 0;
        ((ushort4*)Wib)[i] = z;               // zero-pad row 1023
    } else if (i < 40960) {
        float4 v = ((const float4*)Wl)[i - 32768];
        ushort4 w; w.x = f2bf(v.x); w.y = f2bf(v.y); w.z = f2bf(v.z); w.w = f2bf(v.w);
        ((ushort4*)Wlb)[i - 32768] = w;
    } else if (i < 41216) {
        int j = (i - 40960) * 4;
        float4 z; z.x = 0.f; z.y = 0.f; z.z = 0.f; z.w = 0.f;
        *(float4*)(Sleaf + j) = z;            // zero Sleaf for k_reduce atomics
    }
}

// ---------------------------------------------------------------------------
// k_fused: per 16-row block (256 threads, 4 waves), 37 KB LDS -> 4 blocks/CU:
//   phase G: p = sigmoid(data16x128 @ Wib^T) -> LDS (bf16, heap +1 shift,
//            XOR-swizzled). 4 waves, each owns 256 p-cols; Wib streamed from L2.
//   phase T: register tree (16 lanes per row) reading p from LDS; leaves
//            overwrite the p panel (bf16).
//   phase S: leaf column sums -> part (contention-free); GEMM2 = leaves @ Wlb^T.
// (mechanical 32->16-row transform of the verified round-6 kernel; LDS-staged
//  A and f2bf kept deliberately — R3's direct-A / cvtpk deltas excluded)
// ---------------------------------------------------------------------------
__global__ __launch_bounds__(256, 4) void k_fused(const float* __restrict__ data,
                                                  const unsigned short* __restrict__ Wib,
                                                  const unsigned short* __restrict__ Wlb,
                                                  float* __restrict__ out,
                                                  float* __restrict__ part) {
    __shared__ __align__(16) char lds[32768 + 4352];
    char* lp = lds;                                           // p / leaves / pc
    unsigned short (*As)[136] = (unsigned short(*)[136])(lds + 32768);
    const int tid = threadIdx.x;
    const int blk = blockIdx.x;                 // 4096 blocks x 16 rows

    // ---- stage A: 16x128 f32 -> bf16 LDS ----
    const float4* Ag = (const float4*)(data + (size_t)blk * 16 * 128);
#pragma unroll
    for (int i = 0; i < 2; ++i) {
        int idx = tid + 256 * i;             // 512 float4
        float4 v = Ag[idx];
        int e = idx << 2, row = e >> 7, col = e & 127;
        ushort4 w; w.x = f2bf(v.x); w.y = f2bf(v.y); w.z = f2bf(v.z); w.w = f2bf(v.w);
        *(ushort4*)&As[row][col] = w;
    }
    __syncthreads();

    const int w = tid >> 6, lane = tid & 63;
    const int lr = lane & 15, hi = lane >> 4;

    // ---- phase G: GEMM M=16 N=1024 (each wave 256 cols) K=128 ----
    f32x4 acc[16] = {};
#pragma unroll
    for (int ks = 0; ks < 4; ++ks) {
        bf16x8 a0 = *(const bf16x8*)&As[lr][ks * 32 + hi * 8];
#pragma unroll
        for (int fj = 0; fj < 16; ++fj) {
            const unsigned short* bp =
                Wib + (size_t)(w * 256 + fj * 16 + lr) * 128 + ks * 32 + hi * 8;
            bf16x8 b = *(const bf16x8*)bp;
            // swapped operands: D-"row" = n (p col), D-"col" = m (batch row)
            acc[fj] = __builtin_amdgcn_mfma_f32_16x16x32_bf16(b, a0, acc[fj], 0, 0, 0);
        }
    }

    // ---- sigmoid -> bf16 -> LDS p (heap-shifted +1, swizzled) ----
    {
        const int m = lr;
        int prev = 0;
#pragma unroll
        for (int fj = 0; fj < 16; ++fj) {
            unsigned short v[4];
#pragma unroll
            for (int r = 0; r < 4; ++r) {
                float x = acc[fj][r];
                v[r] = f2bf(__builtin_amdgcn_rcpf(1.f + __expf(-x)));
            }
            int cur = __shfl((int)v[3], (lane + 48) & 63, 64);
            const int n0 = w * 256 + fj * 16 + hi * 4;
            if (fj == 0 && hi == 0) {
                // cols n0+1..n0+3 (col n0 = w*256 written by wave w-1's tail; col 0 unused)
                *(unsigned short*)(lp + lswz(m, 2 * n0 + 2)) = v[0];
                *(unsigned int*)(lp + lswz(m, 2 * n0 + 4)) =
                    (unsigned int)v[1] | ((unsigned int)v[2] << 16);
            } else {
                unsigned short pv = (unsigned short)(hi == 0 ? prev : cur);
                uint2 d;
                d.x = (unsigned int)pv | ((unsigned int)v[0] << 16);
                d.y = (unsigned int)v[1] | ((unsigned int)v[2] << 16);
                *(uint2*)(lp + lswz(m, 2 * n0)) = d;   // cols n0..n0+3
            }
            if (fj == 15 && hi == 3 && w < 3)          // tail col (w+1)*256
                *(unsigned short*)(lp + lswz(m, 2 * (w * 256 + 256))) = v[3];
            prev = cur;
        }
    }
    __syncthreads();

    // ---- phase T: register tree. group g = row (16 rows), 16 lanes each ----
    const int g = tid >> 4, l = tid & 15;

    // path product to level-4 node (heap col 16+l)
    const int node = 16 + l;
    float m0 = 1.f;
#pragma unroll
    for (int k = 3; k >= 0; --k) {
        int anc = node >> (k + 1);
        int b = (node >> k) & 1;
        float pv = bf2f(*(const unsigned short*)(lp + lswz(g, 2 * anc)));
        m0 *= b ? (1.f - pv) : pv;
    }
    float M[32];
    M[0] = m0;
    // L=4 (col 16+l)
    { float pv = bf2f(*(const unsigned short*)(lp + lswz(g, 32 + 2 * l)));
      float e = M[0] * pv; M[1] = M[0] - e; M[0] = e; }
    // L=5 (cols 32+2l)
    { unsigned int u = *(const unsigned int*)(lp + lswz(g, 64 + 4 * l));
      float e1 = M[1] * bfu_hi(u); M[3] = M[1] - e1; M[2] = e1;
      float e0 = M[0] * bfu_lo(u); M[1] = M[0] - e0; M[0] = e0; }
    // L=6 (cols 64+4l)
    { uint2 u = *(const uint2*)(lp + lswz(g, 128 + 8 * l));
      float pv[4] = { bfu_lo(u.x), bfu_hi(u.x), bfu_lo(u.y), bfu_hi(u.y) };
#pragma unroll
      for (int j = 3; j >= 0; --j) {
          float e = M[j] * pv[j]; M[2 * j + 1] = M[j] - e; M[2 * j] = e;
      } }
    // L=7 (cols 128+8l)
    { uint4 u = *(const uint4*)(lp + lswz(g, 256 + 16 * l));
      float pv[8] = { bfu_lo(u.x), bfu_hi(u.x), bfu_lo(u.y), bfu_hi(u.y),
                      bfu_lo(u.z), bfu_hi(u.z), bfu_lo(u.w), bfu_hi(u.w) };
#pragma unroll
      for (int j = 7; j >= 0; --j) {
          float e = M[j] * pv[j]; M[2 * j + 1] = M[j] - e; M[2 * j] = e;
      } }
    // L=8 (cols 256+16l)
    { uint4 ua = *(const uint4*)(lp + lswz(g, 512 + 32 * l));
      uint4 ub = *(const uint4*)(lp + lswz(g, 512 + 32 * l + 16));
      float pv[16] = { bfu_lo(ua.x), bfu_hi(ua.x), bfu_lo(ua.y), bfu_hi(ua.y),
                       bfu_lo(ua.z), bfu_hi(ua.z), bfu_lo(ua.w), bfu_hi(ua.w),
                       bfu_lo(ub.x), bfu_hi(ub.x), bfu_lo(ub.y), bfu_hi(ub.y),
                       bfu_lo(ub.z), bfu_hi(ub.z), bfu_lo(ub.w), bfu_hi(ub.w) };
#pragma unroll
      for (int j = 15; j >= 0; --j) {
          float e = M[j] * pv[j]; M[2 * j + 1] = M[j] - e; M[2 * j] = e;
      } }

    // L=9: read p first, then overwrite panel with bf16 leaves
    uint4 u9[4];
#pragma unroll
    for (int c = 0; c < 4; ++c)
        u9[c] = *(const uint4*)(lp + lswz(g, 1024 + 64 * l + 16 * c));
    __builtin_amdgcn_sched_barrier(0);   // keep leaf writes after p reads
#pragma unroll
    for (int c = 0; c < 4; ++c) {
        float pv[8] = { bfu_lo(u9[c].x), bfu_hi(u9[c].x), bfu_lo(u9[c].y), bfu_hi(u9[c].y),
                        bfu_lo(u9[c].z), bfu_hi(u9[c].z), bfu_lo(u9[c].w), bfu_hi(u9[c].w) };
        unsigned int wd[8];
#pragma unroll
        for (int jj = 0; jj < 8; ++jj) {
            float mu = M[8 * c + jj];
            float e = mu * pv[jj];
            float o = mu - e;
            wd[jj] = (unsigned int)f2bf(e) | ((unsigned int)f2bf(o) << 16);
        }
        const int cb = 128 * l + 32 * c;
        uint4 w0 = make_uint4(wd[0], wd[1], wd[2], wd[3]);
        uint4 w1 = make_uint4(wd[4], wd[5], wd[6], wd[7]);
        *(uint4*)(lp + lswz(g, cb)) = w0;
        *(uint4*)(lp + lswz(g, cb + 16)) = w1;
    }
    __syncthreads();

    // ---- phase S: column sums over 16 rows -> part (contention-free) ----
    {
        float4 cs; cs.x = 0.f; cs.y = 0.f; cs.z = 0.f; cs.w = 0.f;
#pragma unroll
        for (int r = 0; r < 16; ++r) {
            uint2 u = *(const uint2*)(lp + lswz(r, 8 * tid));
            cs.x += bfu_lo(u.x); cs.y += bfu_hi(u.x);
            cs.z += bfu_lo(u.y); cs.w += bfu_hi(u.y);
        }
        *(float4*)(part + (size_t)blk * 1024 + 4 * tid) = cs;
    }

    // ---- GEMM2: out[16][32] = leaves @ Wlb^T, 4 waves split K=1024 ----
    f32x4 acc2[2] = {};
#pragma unroll
    for (int ks = 0; ks < 8; ++ks) {
        const int kcol = w * 256 + ks * 32 + hi * 8;
        bf16x8 av = *(const bf16x8*)(lp + lswz(lr, 2 * kcol));
#pragma unroll
        for (int fj = 0; fj < 2; ++fj) {
            bf16x8 bv = *(const bf16x8*)(Wlb + (size_t)(fj * 16 + lr) * 1024 + kcol);
            acc2[fj] = __builtin_amdgcn_mfma_f32_16x16x32_bf16(av, bv, acc2[fj], 0, 0, 0);
        }
    }
    __syncthreads();   // all panel reads done; overlay pc partials
    float* pc = (float*)lds;   // [4][16][32] f32 = 8 KB
#pragma unroll
    for (int fj = 0; fj < 2; ++fj)
#pragma unroll
        for (int r = 0; r < 4; ++r)
            pc[((size_t)w * 16 + hi * 4 + r) * 32 + fj * 16 + lr] = acc2[fj][r];
    __syncthreads();
    {
        int mm = tid >> 4, nc = (tid & 15) * 2;
        float sx = 0.f, sy = 0.f;
#pragma unroll
        for (int w4 = 0; w4 < 4; ++w4) {
            float2 v = *(const float2*)&pc[((size_t)w4 * 16 + mm) * 32 + nc];
            sx += v.x; sy += v.y;
        }
        float2 s; s.x = sx; s.y = sy;
        *(float2*)(out + ((size_t)blk * 16 + mm) * 32 + nc) = s;
    }
}

// ---------------------------------------------------------------------------
// k_reduce: coalesced — block b sums part rows 16b..16b+15 (float4/thread),
// then 4 atomicAdds into Sleaf (zeroed by k_prep). 256 atomics per address.
// ---------------------------------------------------------------------------
__global__ __launch_bounds__(256) void k_reduce(const float* __restrict__ part,
                                                float* __restrict__ Sleaf) {
    int t = threadIdx.x;
    const float* base = part + (size_t)blockIdx.x * 16 * 1024 + 4 * t;
    float4 s; s.x = 0.f; s.y = 0.f; s.z = 0.f; s.w = 0.f;
#pragma unroll
    for (int r = 0; r < 16; ++r) {
        float4 v = *(const float4*)(base + r * 1024);
        s.x += v.x; s.y += v.y; s.z += v.z; s.w += v.w;
    }
    atomicAdd(&Sleaf[4 * t + 0], s.x);
    atomicAdd(&Sleaf[4 * t + 1], s.y);
    atomicAdd(&Sleaf[4 * t + 2], s.z);
    atomicAdd(&Sleaf[4 * t + 3], s.w);
}

// ---------------------------------------------------------------------------
// k_penalty: node sums up the tree + penalty scalar.
// ---------------------------------------------------------------------------
__global__ __launch_bounds__(256) void k_penalty(const float* __restrict__ Sleaf,
                                                 float* __restrict__ out) {
    __shared__ float S[2047];
    __shared__ float red[4];
    int t = threadIdx.x;
    for (int i = t; i < 1024; i += 256) S[1023 + i] = Sleaf[i];
    __syncthreads();
    for (int L = 9; L >= 0; --L) {
        int o = (1 << L) - 1, n = 1 << L;
        for (int k = t; k < n; k += 256) {
            int gi = o + k;
            S[gi] = S[2 * gi + 1] + S[2 * gi + 2];
        }
        __syncthreads();
    }
    float acc = 0.f;
    for (int gi = 1 + t; gi <= 2046; gi += 256) {
        int lvl = 31 - __clz(gi + 1);
        float wgt = 0.001f * exp2f((float)(1 - lvl)) * 0.5f;
        float al = S[gi] / S[(gi - 1) >> 1];
        acc -= wgt * (logf(al) + log1pf(-al));
    }
#pragma unroll
    for (int o = 32; o > 0; o >>= 1) acc += __shfl_down(acc, o, 64);
    int lane = t & 63, w = t >> 6;
    if (lane == 0) red[w] = acc;
    __syncthreads();
    if (t == 0)
        out[(size_t)SDT_BATCH * 32] = red[0] + red[1] + red[2] + red[3];
}

extern "C" void kernel_launch(void* const* d_in, const int* in_sizes, int n_in,
                              void* d_out, int out_size, void* d_ws, size_t ws_size,
                              hipStream_t stream) {
    const float* data = (const float*)d_in[0]; // [65536][128]
    const float* Wi   = (const float*)d_in[1]; // [1023][128]
    const float* Wl   = (const float*)d_in[2]; // [32][1024]
    float* out = (float*)d_out;

    unsigned short* Wib = (unsigned short*)d_ws;                     // 256 KiB [1024][128]
    unsigned short* Wlb = (unsigned short*)((char*)d_ws + 262144);   // 64 KiB  [32][1024]
    float* Sleaf = (float*)((char*)d_ws + 327680);                   // 4 KiB
    float* part  = (float*)((char*)d_ws + 331776);                   // 16 MiB [4096][1024]

    k_prep<<<161, 256, 0, stream>>>(Wi, Wl, Wib, Wlb, Sleaf);
    k_fused<<<4096, 256, 0, stream>>>(data, Wib, Wlb, out, part);
    k_reduce<<<256, 256, 0, stream>>>(part, Sleaf);
    k_penalty<<<1, 256, 0, stream>>>(Sleaf, out);
}

// Round 8
// 181.460 us; speedup vs baseline: 1.4414x; 1.4414x over previous
//
#include <hip/hip_runtime.h>

typedef float f32x4 __attribute__((ext_vector_type(4)));
typedef short bf16x8 __attribute__((ext_vector_type(8)));

#define SDT_BATCH 65536

__device__ __forceinline__ unsigned short f2bf(float f) {
    union { float f; unsigned int u; } x; x.f = f;
    unsigned int r = (x.u + 0x7fffu + ((x.u >> 16) & 1u)) >> 16;
    return (unsigned short)r;
}
__device__ __forceinline__ float bf2f(unsigned short h) {
    union { unsigned int u; float f; } x; x.u = ((unsigned int)h) << 16;
    return x.f;
}
__device__ __forceinline__ float bfu_lo(unsigned int u) {
    union { unsigned int i; float f; } x; x.i = u << 16; return x.f;
}
__device__ __forceinline__ float bfu_hi(unsigned int u) {
    union { unsigned int i; float f; } x; x.i = u & 0xffff0000u; return x.f;
}

// swizzled byte offset into the 32-row x 2048B LDS panel
__device__ __forceinline__ int lswz(int row, int b) {
    return row * 2048 + (b ^ ((row & 7) << 4) ^ (((b >> 7) & 7) << 4));
}

// ---------------------------------------------------------------------------
// k_prep: Wi [1023][128] f32 -> Wib [1024][128] bf16 (row 1023 zero),
//         Wl [32][1024] f32 -> Wlb bf16, zero Sleaf[1024].
// ---------------------------------------------------------------------------
__global__ __launch_bounds__(256) void k_prep(const float* __restrict__ Wi,
                                              const float* __restrict__ Wl,
                                              unsigned short* __restrict__ Wib,
                                              unsigned short* __restrict__ Wlb,
                                              float* __restrict__ Sleaf) {
    int i = blockIdx.x * 256 + threadIdx.x;   // 161*256 = 41216 slots
    if (i < 32736) {
        float4 v = ((const float4*)Wi)[i];
        ushort4 w; w.x = f2bf(v.x); w.y = f2bf(v.y); w.z = f2bf(v.z); w.w = f2bf(v.w);
        ((ushort4*)Wib)[i] = w;
    } else if (i < 32768) {
        ushort4 z; z.x = 0; z.y = 0; z.z = 0; z.w = 0;
        ((ushort4*)Wib)[i] = z;               // zero-pad row 1023
    } else if (i < 40960) {
        float4 v = ((const float4*)Wl)[i - 32768];
        ushort4 w; w.x = f2bf(v.x); w.y = f2bf(v.y); w.z = f2bf(v.z); w.w = f2bf(v.w);
        ((ushort4*)Wlb)[i - 32768] = w;
    } else if (i < 41216) {
        int j = (i - 40960) * 4;
        float4 z; z.x = 0.f; z.y = 0.f; z.z = 0.f; z.w = 0.f;
        *(float4*)(Sleaf + j) = z;            // zero Sleaf for k_reduce atomics
    }
}

// ---------------------------------------------------------------------------
// k_fused: per 32-row block (512 threads, 8 waves) — verified R6 structure,
// with phase G restructured for 8-deep batched B-register prefetch:
//   - bb[8] holds one ks-slice of B fragments (32 VGPRs, 8 loads in flight)
//   - ks=0 batch issued BEFORE the stage-A barrier (hides behind staging)
// Everything else byte-identical to the verified 100 µs kernel.
// ---------------------------------------------------------------------------
__global__ __launch_bounds__(512, 4) void k_fused(const float* __restrict__ data,
                                                  const unsigned short* __restrict__ Wib,
                                                  const unsigned short* __restrict__ Wlb,
                                                  float* __restrict__ out,
                                                  float* __restrict__ part) {
    __shared__ __align__(16) char lds[65536 + 8704];
    char* lp = lds;                                           // p / leaves / pc
    unsigned short (*As)[136] = (unsigned short(*)[136])(lds + 65536);
    const int tid = threadIdx.x;
    const int blk = blockIdx.x;

    const int w = tid >> 6, lane = tid & 63;
    const int lr = lane & 15, hi = lane >> 4;

    // B fragment base for this lane: row (w*128 + fj*16 + lr), col hi*8
    const unsigned short* wbase = Wib + ((size_t)(w * 128 + lr)) * 128 + hi * 8;
    bf16x8 bb[8];

#define LOADB(KS)                                                              \
    do {                                                                       \
        _Pragma("unroll") for (int fj = 0; fj < 8; ++fj)                       \
            bb[fj] = *(const bf16x8*)(wbase + fj * 2048 + (KS) * 32);          \
    } while (0)

#define GEMM_KS(KS)                                                            \
    do {                                                                       \
        bf16x8 a0 = *(const bf16x8*)&As[lr][(KS) * 32 + hi * 8];               \
        bf16x8 a1 = *(const bf16x8*)&As[16 + lr][(KS) * 32 + hi * 8];          \
        _Pragma("unroll") for (int fj = 0; fj < 8; ++fj) {                     \
            acc[0][fj] = __builtin_amdgcn_mfma_f32_16x16x32_bf16(              \
                bb[fj], a0, acc[0][fj], 0, 0, 0);                              \
            acc[1][fj] = __builtin_amdgcn_mfma_f32_16x16x32_bf16(              \
                bb[fj], a1, acc[1][fj], 0, 0, 0);                              \
        }                                                                      \
    } while (0)

    // ---- stage A: 32x128 f32 -> bf16 LDS ----
    const float4* Ag = (const float4*)(data + (size_t)blk * 32 * 128);
#pragma unroll
    for (int i = 0; i < 2; ++i) {
        int idx = tid + 512 * i;             // 1024 float4
        float4 v = Ag[idx];
        int e = idx << 2, row = e >> 7, col = e & 127;
        ushort4 wv; wv.x = f2bf(v.x); wv.y = f2bf(v.y); wv.z = f2bf(v.z); wv.w = f2bf(v.w);
        *(ushort4*)&As[row][col] = wv;
    }
    LOADB(0);            // prefetch ks=0 B batch under the barrier
    __syncthreads();

    // ---- phase G: GEMM M=32 N=1024 (each wave 128 cols) K=128 ----
    f32x4 acc[2][8] = {};
    GEMM_KS(0);
    LOADB(1);
    GEMM_KS(1);
    LOADB(2);
    GEMM_KS(2);
    LOADB(3);
    GEMM_KS(3);
#undef LOADB
#undef GEMM_KS

    // ---- sigmoid -> bf16 -> LDS p (heap-shifted +1, swizzled) ----
#pragma unroll
    for (int fi = 0; fi < 2; ++fi) {
        const int m = fi * 16 + lr;
        int prev = 0;
#pragma unroll
        for (int fj = 0; fj < 8; ++fj) {
            unsigned short v[4];
#pragma unroll
            for (int r = 0; r < 4; ++r) {
                float x = acc[fi][fj][r];
                v[r] = f2bf(__builtin_amdgcn_rcpf(1.f + __expf(-x)));
            }
            int cur = __shfl((int)v[3], (lane + 48) & 63, 64);
            const int n0 = w * 128 + fj * 16 + hi * 4;
            if (fj == 0 && hi == 0) {
                // cols n0+1..n0+3 (col n0 = w*128 written by wave w-1's tail; col 0 unused)
                *(unsigned short*)(lp + lswz(m, 2 * n0 + 2)) = v[0];
                *(unsigned int*)(lp + lswz(m, 2 * n0 + 4)) =
                    (unsigned int)v[1] | ((unsigned int)v[2] << 16);
            } else {
                unsigned short pv = (unsigned short)(hi == 0 ? prev : cur);
                uint2 d;
                d.x = (unsigned int)pv | ((unsigned int)v[0] << 16);
                d.y = (unsigned int)v[1] | ((unsigned int)v[2] << 16);
                *(uint2*)(lp + lswz(m, 2 * n0)) = d;   // cols n0..n0+3
            }
            if (fj == 7 && hi == 3 && w < 7)           // tail col (w+1)*128
                *(unsigned short*)(lp + lswz(m, 2 * (w * 128 + 128))) = v[3];
            prev = cur;
        }
    }
    __syncthreads();

    // ---- phase T: register tree. group g = row, 16 lanes each ----
    const int g = tid >> 4, l = tid & 15;

    // path product to level-4 node (heap col 16+l)
    const int node = 16 + l;
    float m0 = 1.f;
#pragma unroll
    for (int k = 3; k >= 0; --k) {
        int anc = node >> (k + 1);
        int b = (node >> k) & 1;
        float pv = bf2f(*(const unsigned short*)(lp + lswz(g, 2 * anc)));
        m0 *= b ? (1.f - pv) : pv;
    }
    float M[32];
    M[0] = m0;
    // L=4 (col 16+l)
    { float pv = bf2f(*(const unsigned short*)(lp + lswz(g, 32 + 2 * l)));
      float e = M[0] * pv; M[1] = M[0] - e; M[0] = e; }
    // L=5 (cols 32+2l)
    { unsigned int u = *(const unsigned int*)(lp + lswz(g, 64 + 4 * l));
      float e1 = M[1] * bfu_hi(u); M[3] = M[1] - e1; M[2] = e1;
      float e0 = M[0] * bfu_lo(u); M[1] = M[0] - e0; M[0] = e0; }
    // L=6 (cols 64+4l)
    { uint2 u = *(const uint2*)(lp + lswz(g, 128 + 8 * l));
      float pv[4] = { bfu_lo(u.x), bfu_hi(u.x), bfu_lo(u.y), bfu_hi(u.y) };
#pragma unroll
      for (int j = 3; j >= 0; --j) {
          float e = M[j] * pv[j]; M[2 * j + 1] = M[j] - e; M[2 * j] = e;
      } }
    // L=7 (cols 128+8l)
    { uint4 u = *(const uint4*)(lp + lswz(g, 256 + 16 * l));
      float pv[8] = { bfu_lo(u.x), bfu_hi(u.x), bfu_lo(u.y), bfu_hi(u.y),
                      bfu_lo(u.z), bfu_hi(u.z), bfu_lo(u.w), bfu_hi(u.w) };
#pragma unroll
      for (int j = 7; j >= 0; --j) {
          float e = M[j] * pv[j]; M[2 * j + 1] = M[j] - e; M[2 * j] = e;
      } }
    // L=8 (cols 256+16l)
    { uint4 ua = *(const uint4*)(lp + lswz(g, 512 + 32 * l));
      uint4 ub = *(const uint4*)(lp + lswz(g, 512 + 32 * l + 16));
      float pv[16] = { bfu_lo(ua.x), bfu_hi(ua.x), bfu_lo(ua.y), bfu_hi(ua.y),
                       bfu_lo(ua.z), bfu_hi(ua.z), bfu_lo(ua.w), bfu_hi(ua.w),
                       bfu_lo(ub.x), bfu_hi(ub.x), bfu_lo(ub.y), bfu_hi(ub.y),
                       bfu_lo(ub.z), bfu_hi(ub.z), bfu_lo(ub.w), bfu_hi(ub.w) };
#pragma unroll
      for (int j = 15; j >= 0; --j) {
          float e = M[j] * pv[j]; M[2 * j + 1] = M[j] - e; M[2 * j] = e;
      } }

    // L=9: read p first, then overwrite panel with bf16 leaves
    uint4 u9[4];
#pragma unroll
    for (int c = 0; c < 4; ++c)
        u9[c] = *(const uint4*)(lp + lswz(g, 1024 + 64 * l + 16 * c));
    __builtin_amdgcn_sched_barrier(0);   // keep leaf writes after p reads
#pragma unroll
    for (int c = 0; c < 4; ++c) {
        float pv[8] = { bfu_lo(u9[c].x), bfu_hi(u9[c].x), bfu_lo(u9[c].y), bfu_hi(u9[c].y),
                        bfu_lo(u9[c].z), bfu_hi(u9[c].z), bfu_lo(u9[c].w), bfu_hi(u9[c].w) };
        unsigned int wd[8];
#pragma unroll
        for (int jj = 0; jj < 8; ++jj) {
            float mu = M[8 * c + jj];
            float e = mu * pv[jj];
            float o = mu - e;
            wd[jj] = (unsigned int)f2bf(e) | ((unsigned int)f2bf(o) << 16);
        }
        const int cb = 128 * l + 32 * c;
        uint4 w0 = make_uint4(wd[0], wd[1], wd[2], wd[3]);
        uint4 w1 = make_uint4(wd[4], wd[5], wd[6], wd[7]);
        *(uint4*)(lp + lswz(g, cb)) = w0;
        *(uint4*)(lp + lswz(g, cb + 16)) = w1;
    }
    __syncthreads();

    // ---- phase S: column sums over 32 rows -> part (contention-free) ----
    {
        float s0 = 0.f, s1 = 0.f;
#pragma unroll 8
        for (int r = 0; r < 32; ++r) {
            unsigned int u = *(const unsigned int*)(lp + lswz(r, 4 * tid));
            s0 += bfu_lo(u); s1 += bfu_hi(u);
        }
        float2 s; s.x = s0; s.y = s1;
        *(float2*)(part + (size_t)blk * 1024 + 2 * tid) = s;
    }

    // ---- GEMM2: out[32][32] = leaves @ Wlb^T, 8 waves split K=1024 ----
    f32x4 acc2[2][2] = {};
#pragma unroll
    for (int ks = 0; ks < 4; ++ks) {
        const int kcol = w * 128 + ks * 32 + hi * 8;
        bf16x8 a[2], b[2];
#pragma unroll
        for (int fi = 0; fi < 2; ++fi)
            a[fi] = *(const bf16x8*)(lp + lswz(fi * 16 + lr, 2 * kcol));
#pragma unroll
        for (int fj = 0; fj < 2; ++fj)
            b[fj] = *(const bf16x8*)(Wlb + (size_t)(fj * 16 + lr) * 1024 + kcol);
#pragma unroll
        for (int fi = 0; fi < 2; ++fi)
#pragma unroll
            for (int fj = 0; fj < 2; ++fj)
                acc2[fi][fj] = __builtin_amdgcn_mfma_f32_16x16x32_bf16(a[fi], b[fj], acc2[fi][fj], 0, 0, 0);
    }
    __syncthreads();   // all panel reads done; overlay pc partials
    float* pc = (float*)lds;   // [8][32][32] f32
#pragma unroll
    for (int fi = 0; fi < 2; ++fi)
#pragma unroll
        for (int fj = 0; fj < 2; ++fj)
#pragma unroll
            for (int r = 0; r < 4; ++r) {
                int mm = fi * 16 + hi * 4 + r;
                int nn = fj * 16 + lr;
                pc[((size_t)w * 32 + mm) * 32 + nn] = acc2[fi][fj][r];
            }
    __syncthreads();
    {
        int mm = tid >> 4, nc = (tid & 15) * 2;
        float sx = 0.f, sy = 0.f;
#pragma unroll
        for (int w8 = 0; w8 < 8; ++w8) {
            float2 v = *(const float2*)&pc[((size_t)w8 * 32 + mm) * 32 + nc];
            sx += v.x; sy += v.y;
        }
        float2 s; s.x = sx; s.y = sy;
        *(float2*)(out + ((size_t)blk * 32 + mm) * 32 + nc) = s;
    }
}

// ---------------------------------------------------------------------------
// k_reduce: coalesced — block b sums part rows 16b..16b+15 (float4/thread),
// then 4 atomicAdds into Sleaf (zeroed by k_prep). 128 atomics per address.
// ---------------------------------------------------------------------------
__global__ __launch_bounds__(256) void k_reduce(const float* __restrict__ part,
                                                float* __restrict__ Sleaf) {
    int t = threadIdx.x;
    const float* base = part + (size_t)blockIdx.x * 16 * 1024 + 4 * t;
    float4 s; s.x = 0.f; s.y = 0.f; s.z = 0.f; s.w = 0.f;
#pragma unroll
    for (int r = 0; r < 16; ++r) {
        float4 v = *(const float4*)(base + r * 1024);
        s.x += v.x; s.y += v.y; s.z += v.z; s.w += v.w;
    }
    atomicAdd(&Sleaf[4 * t + 0], s.x);
    atomicAdd(&Sleaf[4 * t + 1], s.y);
    atomicAdd(&Sleaf[4 * t + 2], s.z);
    atomicAdd(&Sleaf[4 * t + 3], s.w);
}

// ---------------------------------------------------------------------------
// k_penalty: node sums up the tree + penalty scalar.
// ---------------------------------------------------------------------------
__global__ __launch_bounds__(256) void k_penalty(const float* __restrict__ Sleaf,
                                                 float* __restrict__ out) {
    __shared__ float S[2047];
    __shared__ float red[4];
    int t = threadIdx.x;
    for (int i = t; i < 1024; i += 256) S[1023 + i] = Sleaf[i];
    __syncthreads();
    for (int L = 9; L >= 0; --L) {
        int o = (1 << L) - 1, n = 1 << L;
        for (int k = t; k < n; k += 256) {
            int gi = o + k;
            S[gi] = S[2 * gi + 1] + S[2 * gi + 2];
        }
        __syncthreads();
    }
    float acc = 0.f;
    for (int gi = 1 + t; gi <= 2046; gi += 256) {
        int lvl = 31 - __clz(gi + 1);
        float wgt = 0.001f * exp2f((float)(1 - lvl)) * 0.5f;
        float al = S[gi] / S[(gi - 1) >> 1];
        acc -= wgt * (logf(al) + log1pf(-al));
    }
#pragma unroll
    for (int o = 32; o > 0; o >>= 1) acc += __shfl_down(acc, o, 64);
    int lane = t & 63, w = t >> 6;
    if (lane == 0) red[w] = acc;
    __syncthreads();
    if (t == 0)
        out[(size_t)SDT_BATCH * 32] = red[0] + red[1] + red[2] + red[3];
}

extern "C" void kernel_launch(void* const* d_in, const int* in_sizes, int n_in,
                              void* d_out, int out_size, void* d_ws, size_t ws_size,
                              hipStream_t stream) {
    const float* data = (const float*)d_in[0]; // [65536][128]
    const float* Wi   = (const float*)d_in[1]; // [1023][128]
    const float* Wl   = (const float*)d_in[2]; // [32][1024]
    float* out = (float*)d_out;

    unsigned short* Wib = (unsigned short*)d_ws;                     // 256 KiB [1024][128]
    unsigned short* Wlb = (unsigned short*)((char*)d_ws + 262144);   // 64 KiB  [32][1024]
    float* Sleaf = (float*)((char*)d_ws + 327680);                   // 4 KiB
    float* part  = (float*)((char*)d_ws + 331776);                   // 8 MiB [2048][1024]

    k_prep<<<161, 256, 0, stream>>>(Wi, Wl, Wib, Wlb, Sleaf);
    k_fused<<<2048, 512, 0, stream>>>(data, Wib, Wlb, out, part);
    k_reduce<<<128, 256, 0, stream>>>(part, Sleaf);
    k_penalty<<<1, 256, 0, stream>>>(Sleaf, out);
}

// Round 9
// 155.339 us; speedup vs baseline: 1.6838x; 1.1682x over previous
//
#include <hip/hip_runtime.h>

typedef float f32x4 __attribute__((ext_vector_type(4)));
typedef short bf16x8 __attribute__((ext_vector_type(8)));

#define SDT_BATCH 65536

__device__ __forceinline__ unsigned short f2bf(float f) {
    union { float f; unsigned int u; } x; x.f = f;
    unsigned int r = (x.u + 0x7fffu + ((x.u >> 16) & 1u)) >> 16;
    return (unsigned short)r;
}
__device__ __forceinline__ float bf2f(unsigned short h) {
    union { unsigned int u; float f; } x; x.u = ((unsigned int)h) << 16;
    return x.f;
}
__device__ __forceinline__ float bfu_lo(unsigned int u) {
    union { unsigned int i; float f; } x; x.i = u << 16; return x.f;
}
__device__ __forceinline__ float bfu_hi(unsigned int u) {
    union { unsigned int i; float f; } x; x.i = u & 0xffff0000u; return x.f;
}

// swizzled byte offset into the 32-row x 2048B LDS panel
__device__ __forceinline__ int lswz(int row, int b) {
    return row * 2048 + (b ^ ((row & 7) << 4) ^ (((b >> 7) & 7) << 4));
}

// ---------------------------------------------------------------------------
// k_prep: Wi [1023][128] f32 -> Wib bf16 in FRAGMENT ORDER:
//   group (fj' in [0,64), ks in [0,4), lane in [0,64)) at
//   dst = ((fj'*4+ks)*64 + lane)*8 shorts holds Wi[fj'*16+(lane&15)]
//         [ks*32+(lane>>4)*8 .. +7]   (row 1023 -> zeros).
// Also Wl [32][1024] f32 -> Wlb bf16, zero Sleaf[1024].
// ---------------------------------------------------------------------------
__global__ __launch_bounds__(256) void k_prep(const float* __restrict__ Wi,
                                              const float* __restrict__ Wl,
                                              unsigned short* __restrict__ Wib,
                                              unsigned short* __restrict__ Wlb,
                                              float* __restrict__ Sleaf) {
    int i = blockIdx.x * 256 + threadIdx.x;   // 97*256 = 24832 slots
    if (i < 16384) {
        // Wib fragment group i: row = i>>4, col-group = i&15
        int row = i >> 4, cg = i & 15;
        int fjp = row >> 4, lr = row & 15;
        int ks = cg >> 2, hi = cg & 3;
        int lane = hi * 16 + lr;
        unsigned short* dst = Wib + ((size_t)((fjp * 4 + ks) * 64 + lane)) * 8;
        if (row < 1023) {
            const float* src = Wi + (size_t)row * 128 + cg * 8;
            float4 v0 = *(const float4*)src;
            float4 v1 = *(const float4*)(src + 4);
            ushort4 w0, w1;
            w0.x = f2bf(v0.x); w0.y = f2bf(v0.y); w0.z = f2bf(v0.z); w0.w = f2bf(v0.w);
            w1.x = f2bf(v1.x); w1.y = f2bf(v1.y); w1.z = f2bf(v1.z); w1.w = f2bf(v1.w);
            *(ushort4*)dst = w0;
            *(ushort4*)(dst + 4) = w1;
        } else {
            ushort4 z; z.x = 0; z.y = 0; z.z = 0; z.w = 0;
            *(ushort4*)dst = z;
            *(ushort4*)(dst + 4) = z;
        }
    } else if (i < 24576) {
        int j = i - 16384;
        float4 v = ((const float4*)Wl)[j];
        ushort4 w; w.x = f2bf(v.x); w.y = f2bf(v.y); w.z = f2bf(v.z); w.w = f2bf(v.w);
        ((ushort4*)Wlb)[j] = w;
    } else if (i < 24832) {
        int j = (i - 24576) * 4;
        float4 z; z.x = 0.f; z.y = 0.f; z.z = 0.f; z.w = 0.f;
        *(float4*)(Sleaf + j) = z;            // zero Sleaf for k_reduce atomics
    }
}

// ---------------------------------------------------------------------------
// k_fused: per 32-row block (512 threads, 8 waves) — verified R8 structure,
// phase G now reads Wib in fragment order: each wave load instruction is a
// single contiguous 1 KB segment (64 lanes x 16 B), 16x fewer L2 requests.
// Everything else byte-identical to the verified ~97 µs kernel.
// ---------------------------------------------------------------------------
__global__ __launch_bounds__(512, 4) void k_fused(const float* __restrict__ data,
                                                  const unsigned short* __restrict__ Wib,
                                                  const unsigned short* __restrict__ Wlb,
                                                  float* __restrict__ out,
                                                  float* __restrict__ part) {
    __shared__ __align__(16) char lds[65536 + 8704];
    char* lp = lds;                                           // p / leaves / pc
    unsigned short (*As)[136] = (unsigned short(*)[136])(lds + 65536);
    const int tid = threadIdx.x;
    const int blk = blockIdx.x;

    const int w = tid >> 6, lane = tid & 63;
    const int lr = lane & 15, hi = lane >> 4;

    // fragment-order B base: wave w, this lane
    const unsigned short* wbase = Wib + (size_t)w * 16384 + (size_t)lane * 8;
    bf16x8 bb[8];

#define LOADB(KS)                                                              \
    do {                                                                       \
        _Pragma("unroll") for (int fj = 0; fj < 8; ++fj)                       \
            bb[fj] = *(const bf16x8*)(wbase + fj * 2048 + (KS) * 512);         \
    } while (0)

#define GEMM_KS(KS)                                                            \
    do {                                                                       \
        bf16x8 a0 = *(const bf16x8*)&As[lr][(KS) * 32 + hi * 8];               \
        bf16x8 a1 = *(const bf16x8*)&As[16 + lr][(KS) * 32 + hi * 8];          \
        _Pragma("unroll") for (int fj = 0; fj < 8; ++fj) {                     \
            acc[0][fj] = __builtin_amdgcn_mfma_f32_16x16x32_bf16(              \
                bb[fj], a0, acc[0][fj], 0, 0, 0);                              \
            acc[1][fj] = __builtin_amdgcn_mfma_f32_16x16x32_bf16(              \
                bb[fj], a1, acc[1][fj], 0, 0, 0);                              \
        }                                                                      \
    } while (0)

    // ---- stage A: 32x128 f32 -> bf16 LDS ----
    const float4* Ag = (const float4*)(data + (size_t)blk * 32 * 128);
#pragma unroll
    for (int i = 0; i < 2; ++i) {
        int idx = tid + 512 * i;             // 1024 float4
        float4 v = Ag[idx];
        int e = idx << 2, row = e >> 7, col = e & 127;
        ushort4 wv; wv.x = f2bf(v.x); wv.y = f2bf(v.y); wv.z = f2bf(v.z); wv.w = f2bf(v.w);
        *(ushort4*)&As[row][col] = wv;
    }
    LOADB(0);            // prefetch ks=0 B batch under the barrier
    __syncthreads();

    // ---- phase G: GEMM M=32 N=1024 (each wave 128 cols) K=128 ----
    f32x4 acc[2][8] = {};
    GEMM_KS(0);
    LOADB(1);
    GEMM_KS(1);
    LOADB(2);
    GEMM_KS(2);
    LOADB(3);
    GEMM_KS(3);
#undef LOADB
#undef GEMM_KS

    // ---- sigmoid -> bf16 -> LDS p (heap-shifted +1, swizzled) ----
#pragma unroll
    for (int fi = 0; fi < 2; ++fi) {
        const int m = fi * 16 + lr;
        int prev = 0;
#pragma unroll
        for (int fj = 0; fj < 8; ++fj) {
            unsigned short v[4];
#pragma unroll
            for (int r = 0; r < 4; ++r) {
                float x = acc[fi][fj][r];
                v[r] = f2bf(__builtin_amdgcn_rcpf(1.f + __expf(-x)));
            }
            int cur = __shfl((int)v[3], (lane + 48) & 63, 64);
            const int n0 = w * 128 + fj * 16 + hi * 4;
            if (fj == 0 && hi == 0) {
                // cols n0+1..n0+3 (col n0 = w*128 written by wave w-1's tail; col 0 unused)
                *(unsigned short*)(lp + lswz(m, 2 * n0 + 2)) = v[0];
                *(unsigned int*)(lp + lswz(m, 2 * n0 + 4)) =
                    (unsigned int)v[1] | ((unsigned int)v[2] << 16);
            } else {
                unsigned short pv = (unsigned short)(hi == 0 ? prev : cur);
                uint2 d;
                d.x = (unsigned int)pv | ((unsigned int)v[0] << 16);
                d.y = (unsigned int)v[1] | ((unsigned int)v[2] << 16);
                *(uint2*)(lp + lswz(m, 2 * n0)) = d;   // cols n0..n0+3
            }
            if (fj == 7 && hi == 3 && w < 7)           // tail col (w+1)*128
                *(unsigned short*)(lp + lswz(m, 2 * (w * 128 + 128))) = v[3];
            prev = cur;
        }
    }
    __syncthreads();

    // ---- phase T: register tree. group g = row, 16 lanes each ----
    const int g = tid >> 4, l = tid & 15;

    // path product to level-4 node (heap col 16+l)
    const int node = 16 + l;
    float m0 = 1.f;
#pragma unroll
    for (int k = 3; k >= 0; --k) {
        int anc = node >> (k + 1);
        int b = (node >> k) & 1;
        float pv = bf2f(*(const unsigned short*)(lp + lswz(g, 2 * anc)));
        m0 *= b ? (1.f - pv) : pv;
    }
    float M[32];
    M[0] = m0;
    // L=4 (col 16+l)
    { float pv = bf2f(*(const unsigned short*)(lp + lswz(g, 32 + 2 * l)));
      float e = M[0] * pv; M[1] = M[0] - e; M[0] = e; }
    // L=5 (cols 32+2l)
    { unsigned int u = *(const unsigned int*)(lp + lswz(g, 64 + 4 * l));
      float e1 = M[1] * bfu_hi(u); M[3] = M[1] - e1; M[2] = e1;
      float e0 = M[0] * bfu_lo(u); M[1] = M[0] - e0; M[0] = e0; }
    // L=6 (cols 64+4l)
    { uint2 u = *(const uint2*)(lp + lswz(g, 128 + 8 * l));
      float pv[4] = { bfu_lo(u.x), bfu_hi(u.x), bfu_lo(u.y), bfu_hi(u.y) };
#pragma unroll
      for (int j = 3; j >= 0; --j) {
          float e = M[j] * pv[j]; M[2 * j + 1] = M[j] - e; M[2 * j] = e;
      } }
    // L=7 (cols 128+8l)
    { uint4 u = *(const uint4*)(lp + lswz(g, 256 + 16 * l));
      float pv[8] = { bfu_lo(u.x), bfu_hi(u.x), bfu_lo(u.y), bfu_hi(u.y),
                      bfu_lo(u.z), bfu_hi(u.z), bfu_lo(u.w), bfu_hi(u.w) };
#pragma unroll
      for (int j = 7; j >= 0; --j) {
          float e = M[j] * pv[j]; M[2 * j + 1] = M[j] - e; M[2 * j] = e;
      } }
    // L=8 (cols 256+16l)
    { uint4 ua = *(const uint4*)(lp + lswz(g, 512 + 32 * l));
      uint4 ub = *(const uint4*)(lp + lswz(g, 512 + 32 * l + 16));
      float pv[16] = { bfu_lo(ua.x), bfu_hi(ua.x), bfu_lo(ua.y), bfu_hi(ua.y),
                       bfu_lo(ua.z), bfu_hi(ua.z), bfu_lo(ua.w), bfu_hi(ua.w),
                       bfu_lo(ub.x), bfu_hi(ub.x), bfu_lo(ub.y), bfu_hi(ub.y),
                       bfu_lo(ub.z), bfu_hi(ub.z), bfu_lo(ub.w), bfu_hi(ub.w) };
#pragma unroll
      for (int j = 15; j >= 0; --j) {
          float e = M[j] * pv[j]; M[2 * j + 1] = M[j] - e; M[2 * j] = e;
      } }

    // L=9: read p first, then overwrite panel with bf16 leaves
    uint4 u9[4];
#pragma unroll
    for (int c = 0; c < 4; ++c)
        u9[c] = *(const uint4*)(lp + lswz(g, 1024 + 64 * l + 16 * c));
    __builtin_amdgcn_sched_barrier(0);   // keep leaf writes after p reads
#pragma unroll
    for (int c = 0; c < 4; ++c) {
        float pv[8] = { bfu_lo(u9[c].x), bfu_hi(u9[c].x), bfu_lo(u9[c].y), bfu_hi(u9[c].y),
                        bfu_lo(u9[c].z), bfu_hi(u9[c].z), bfu_lo(u9[c].w), bfu_hi(u9[c].w) };
        unsigned int wd[8];
#pragma unroll
        for (int jj = 0; jj < 8; ++jj) {
            float mu = M[8 * c + jj];
            float e = mu * pv[jj];
            float o = mu - e;
            wd[jj] = (unsigned int)f2bf(e) | ((unsigned int)f2bf(o) << 16);
        }
        const int cb = 128 * l + 32 * c;
        uint4 w0 = make_uint4(wd[0], wd[1], wd[2], wd[3]);
        uint4 w1 = make_uint4(wd[4], wd[5], wd[6], wd[7]);
        *(uint4*)(lp + lswz(g, cb)) = w0;
        *(uint4*)(lp + lswz(g, cb + 16)) = w1;
    }
    __syncthreads();

    // ---- phase S: column sums over 32 rows -> part (contention-free) ----
    {
        float s0 = 0.f, s1 = 0.f;
#pragma unroll 8
        for (int r = 0; r < 32; ++r) {
            unsigned int u = *(const unsigned int*)(lp + lswz(r, 4 * tid));
            s0 += bfu_lo(u); s1 += bfu_hi(u);
        }
        float2 s; s.x = s0; s.y = s1;
        *(float2*)(part + (size_t)blk * 1024 + 2 * tid) = s;
    }

    // ---- GEMM2: out[32][32] = leaves @ Wlb^T, 8 waves split K=1024 ----
    f32x4 acc2[2][2] = {};
#pragma unroll
    for (int ks = 0; ks < 4; ++ks) {
        const int kcol = w * 128 + ks * 32 + hi * 8;
        bf16x8 a[2], b[2];
#pragma unroll
        for (int fi = 0; fi < 2; ++fi)
            a[fi] = *(const bf16x8*)(lp + lswz(fi * 16 + lr, 2 * kcol));
#pragma unroll
        for (int fj = 0; fj < 2; ++fj)
            b[fj] = *(const bf16x8*)(Wlb + (size_t)(fj * 16 + lr) * 1024 + kcol);
#pragma unroll
        for (int fi = 0; fi < 2; ++fi)
#pragma unroll
            for (int fj = 0; fj < 2; ++fj)
                acc2[fi][fj] = __builtin_amdgcn_mfma_f32_16x16x32_bf16(a[fi], b[fj], acc2[fi][fj], 0, 0, 0);
    }
    __syncthreads();   // all panel reads done; overlay pc partials
    float* pc = (float*)lds;   // [8][32][32] f32
#pragma unroll
    for (int fi = 0; fi < 2; ++fi)
#pragma unroll
        for (int fj = 0; fj < 2; ++fj)
#pragma unroll
            for (int r = 0; r < 4; ++r) {
                int mm = fi * 16 + hi * 4 + r;
                int nn = fj * 16 + lr;
                pc[((size_t)w * 32 + mm) * 32 + nn] = acc2[fi][fj][r];
            }
    __syncthreads();
    {
        int mm = tid >> 4, nc = (tid & 15) * 2;
        float sx = 0.f, sy = 0.f;
#pragma unroll
        for (int w8 = 0; w8 < 8; ++w8) {
            float2 v = *(const float2*)&pc[((size_t)w8 * 32 + mm) * 32 + nc];
            sx += v.x; sy += v.y;
        }
        float2 s; s.x = sx; s.y = sy;
        *(float2*)(out + ((size_t)blk * 32 + mm) * 32 + nc) = s;
    }
}

// ---------------------------------------------------------------------------
// k_reduce: coalesced — block b sums part rows 16b..16b+15 (float4/thread),
// then 4 atomicAdds into Sleaf (zeroed by k_prep). 128 atomics per address.
// ---------------------------------------------------------------------------
__global__ __launch_bounds__(256) void k_reduce(const float* __restrict__ part,
                                                float* __restrict__ Sleaf) {
    int t = threadIdx.x;
    const float* base = part + (size_t)blockIdx.x * 16 * 1024 + 4 * t;
    float4 s; s.x = 0.f; s.y = 0.f; s.z = 0.f; s.w = 0.f;
#pragma unroll
    for (int r = 0; r < 16; ++r) {
        float4 v = *(const float4*)(base + r * 1024);
        s.x += v.x; s.y += v.y; s.z += v.z; s.w += v.w;
    }
    atomicAdd(&Sleaf[4 * t + 0], s.x);
    atomicAdd(&Sleaf[4 * t + 1], s.y);
    atomicAdd(&Sleaf[4 * t + 2], s.z);
    atomicAdd(&Sleaf[4 * t + 3], s.w);
}

// ---------------------------------------------------------------------------
// k_penalty: node sums up the tree + penalty scalar.
// ---------------------------------------------------------------------------
__global__ __launch_bounds__(256) void k_penalty(const float* __restrict__ Sleaf,
                                                 float* __restrict__ out) {
    __shared__ float S[2047];
    __shared__ float red[4];
    int t = threadIdx.x;
    for (int i = t; i < 1024; i += 256) S[1023 + i] = Sleaf[i];
    __syncthreads();
    for (int L = 9; L >= 0; --L) {
        int o = (1 << L) - 1, n = 1 << L;
        for (int k = t; k < n; k += 256) {
            int gi = o + k;
            S[gi] = S[2 * gi + 1] + S[2 * gi + 2];
        }
        __syncthreads();
    }
    float acc = 0.f;
    for (int gi = 1 + t; gi <= 2046; gi += 256) {
        int lvl = 31 - __clz(gi + 1);
        float wgt = 0.001f * exp2f((float)(1 - lvl)) * 0.5f;
        float al = S[gi] / S[(gi - 1) >> 1];
        acc -= wgt * (logf(al) + log1pf(-al));
    }
#pragma unroll
    for (int o = 32; o > 0; o >>= 1) acc += __shfl_down(acc, o, 64);
    int lane = t & 63, w = t >> 6;
    if (lane == 0) red[w] = acc;
    __syncthreads();
    if (t == 0)
        out[(size_t)SDT_BATCH * 32] = red[0] + red[1] + red[2] + red[3];
}

extern "C" void kernel_launch(void* const* d_in, const int* in_sizes, int n_in,
                              void* d_out, int out_size, void* d_ws, size_t ws_size,
                              hipStream_t stream) {
    const float* data = (const float*)d_in[0]; // [65536][128]
    const float* Wi   = (const float*)d_in[1]; // [1023][128]
    const float* Wl   = (const float*)d_in[2]; // [32][1024]
    float* out = (float*)d_out;

    unsigned short* Wib = (unsigned short*)d_ws;                     // 256 KiB fragment-order
    unsigned short* Wlb = (unsigned short*)((char*)d_ws + 262144);   // 64 KiB  [32][1024]
    float* Sleaf = (float*)((char*)d_ws + 327680);                   // 4 KiB
    float* part  = (float*)((char*)d_ws + 331776);                   // 8 MiB [2048][1024]

    k_prep<<<97, 256, 0, stream>>>(Wi, Wl, Wib, Wlb, Sleaf);
    k_fused<<<2048, 512, 0, stream>>>(data, Wib, Wlb, out, part);
    k_reduce<<<128, 256, 0, stream>>>(part, Sleaf);
    k_penalty<<<1, 256, 0, stream>>>(Sleaf, out);
}